// Round 1
// baseline (957.004 us; speedup 1.0000x reference)
//
#include <hip/hip_runtime.h>

// Truncated E-step, restructured:
//   z_k = x . w[u_k] + b[u_k]   (w = mu*exp(-lnv), b = logprop - 0.5*sum(mu^2*iv))
//   noise logit == NOISE_LOG_PROP (softmax shift-invariance kills logdet & x'ivx)
//   resp = softmax([z_0..z_9, -2.0]); stats[u_k] += resp_k * [x | 1]
// LDS holds the full 256x129 f32 stats per block; global atomic flush at end.

#define UNITS 256
#define D 128
#define KCAND 10
#define NOISE_LOGIT (-2.0f)
#define STATS_ELEMS (UNITS * (D + 1))  // 33024 floats = 132096 B

template <int CTRL>
__device__ __forceinline__ float dpp_add(float v) {
  // quad_perm lane-xor add: CTRL=0xB1 -> xor1, CTRL=0x4E -> xor2 (free on VALU)
  const int p = __builtin_amdgcn_update_dpp(0, __float_as_int(v), CTRL, 0xF, 0xF, true);
  return v + __int_as_float(p);
}

// ---- prep: w[u][j] = mu*iv, b[u] = logprop - 0.5*sum(mu^2*iv); zero d_out ----
__global__ void prep_kernel(const float* __restrict__ means,
                            const float* __restrict__ log_noise_var,
                            const float* __restrict__ log_prop,
                            float* __restrict__ w,
                            float* __restrict__ b,
                            float* __restrict__ out) {
  const int u = blockIdx.x;
  const int j = threadIdx.x;  // 128 threads
  const float iv = __expf(-log_noise_var[j]);
  const float mu = means[u * D + j];
  const float wv = mu * iv;
  w[u * D + j] = wv;
  float q = mu * wv;  // mu^2 * iv
#pragma unroll
  for (int off = 32; off; off >>= 1) q += __shfl_xor(q, off);
  __shared__ float red[2];
  if ((j & 63) == 0) red[j >> 6] = q;
  __syncthreads();
  if (j == 0) b[u] = log_prop[u] - 0.5f * (red[0] + red[1]);
  // zero the output row this unit owns (129 floats)
  out[u * (D + 1) + j] = 0.f;
  if (j == 0) out[u * (D + 1) + D] = 0.f;
}

// ---- main: 256 blocks x 1024 threads, 1 block/CU (LDS-limited) ----
__global__ void __launch_bounds__(1024) estep_kernel(
    const float* __restrict__ x, const int* __restrict__ cand,
    const float* __restrict__ wmat, const float* __restrict__ bvec,
    float* __restrict__ out, int n) {
  extern __shared__ float sstats[];  // [UNITS][129]
  const int tid = threadIdx.x;
  for (int i = tid; i < STATS_ELEMS; i += 1024) sstats[i] = 0.f;
  __syncthreads();

  const int lane = tid & 63;
  const int wid = tid >> 6;       // 16 waves
  const int g = lane >> 3;        // spike-slot within wave (8 spikes/wave-iter)
  const int l = lane & 7;         // 8 lanes per spike, 16 dims each

  const int spb = n >> 8;         // spikes per block (512 at n=131072)
  const int iters = spb >> 7;     // 8-spike groups per wave (4)
  const int wbase = blockIdx.x * spb + wid * (spb >> 4);

  for (int it = 0; it < iters; ++it) {
    const int spike8 = wbase + it * 8;
    const int spike = spike8 + g;

    // x fragment: dims q*32 + l*4 + i  (per-q: 8 lanes cover contiguous 128B)
    const float* xrow = x + (size_t)spike * D;
    float xv[16];
#pragma unroll
    for (int q = 0; q < 4; ++q) {
      const float4 t = *reinterpret_cast<const float4*>(xrow + q * 32 + l * 4);
      xv[4 * q + 0] = t.x; xv[4 * q + 1] = t.y;
      xv[4 * q + 2] = t.z; xv[4 * q + 3] = t.w;
    }

    // candidate ids (uniform across the 8 lanes of the group)
    int uc[KCAND];
#pragma unroll
    for (int k = 0; k < KCAND; ++k) uc[k] = cand[(size_t)spike * KCAND + k];

    // 10 dot products; 8-lane reduce = 2 DPP adds + 1 swizzle
    float e[KCAND];
#pragma unroll
    for (int k = 0; k < KCAND; ++k) {
      const float* wrow = wmat + (size_t)uc[k] * D;
      float acc = 0.f;
#pragma unroll
      for (int q = 0; q < 4; ++q) {
        const float4 t = *reinterpret_cast<const float4*>(wrow + q * 32 + l * 4);
        acc = fmaf(xv[4 * q + 0], t.x, acc);
        acc = fmaf(xv[4 * q + 1], t.y, acc);
        acc = fmaf(xv[4 * q + 2], t.z, acc);
        acc = fmaf(xv[4 * q + 3], t.w, acc);
      }
      acc = dpp_add<0xB1>(acc);
      acc = dpp_add<0x4E>(acc);
      acc += __shfl_xor(acc, 4);
      e[k] = acc + bvec[uc[k]];
    }

    // softmax over [z_0..z_9, NOISE_LOGIT] (redundant across the 8 lanes: fine)
    float m = NOISE_LOGIT;
#pragma unroll
    for (int k = 0; k < KCAND; ++k) m = fmaxf(m, e[k]);
    float ssum = __expf(NOISE_LOGIT - m);
#pragma unroll
    for (int k = 0; k < KCAND; ++k) { e[k] = __expf(e[k] - m); ssum += e[k]; }
    const float rinv = 1.f / ssum;
#pragma unroll
    for (int k = 0; k < KCAND; ++k) e[k] *= rinv;

    // count column: lane l handles (spike g, cand l); l<2 also (g, 8+l).
    // static select-chain (no dynamic register indexing -> no scratch)
    {
      float rsel = e[0]; int usel = uc[0];
#pragma unroll
      for (int k = 1; k < 8; ++k) {
        const bool p = (l == k);
        rsel = p ? e[k] : rsel;
        usel = p ? uc[k] : usel;
      }
      atomicAdd(&sstats[usel * (D + 1) + D], rsel);
      const float rs2 = (l == 0) ? e[8] : e[9];
      const int us2 = (l == 0) ? uc[8] : uc[9];
      if (l < 2) atomicAdd(&sstats[us2 * (D + 1) + D], rs2);
    }

    // prefetch the 8 x-rows in full-wave layout (L1-hot; coalesced 256B)
    float xsa[8], xsb[8];
#pragma unroll
    for (int s = 0; s < 8; ++s) {
      const float* xr = x + (size_t)(spike8 + s) * D;
      xsa[s] = xr[lane];
      xsb[s] = xr[lane + 64];
    }

    // scatter: full wave per (spike,cand); lanes cover 64 consecutive dims
    // -> exactly 2 lanes/bank per ds_add = conflict-free (m136).
    // resp/unit broadcast via v_readlane (VALU, keeps DS pipe for the adds).
#pragma unroll
    for (int s = 0; s < 8; ++s) {
#pragma unroll
      for (int k = 0; k < KCAND; ++k) {
        const int u = __builtin_amdgcn_readlane(uc[k], s * 8);
        const float r = __int_as_float(
            __builtin_amdgcn_readlane(__float_as_int(e[k]), s * 8));
        float* base = &sstats[u * (D + 1)];
        atomicAdd(base + lane, r * xsa[s]);
        atomicAdd(base + lane + 64, r * xsb[s]);
      }
    }
  }

  __syncthreads();
  for (int i = tid; i < STATS_ELEMS; i += 1024)
    unsafeAtomicAdd(&out[i], sstats[i]);
}

extern "C" void kernel_launch(void* const* d_in, const int* in_sizes, int n_in,
                              void* d_out, int out_size, void* d_ws, size_t ws_size,
                              hipStream_t stream) {
  const float* features = (const float*)d_in[0];
  const float* means    = (const float*)d_in[1];
  const float* lnv      = (const float*)d_in[2];
  const float* lprop    = (const float*)d_in[3];
  const int*   cand     = (const int*)d_in[4];
  float* out = (float*)d_out;

  float* w = (float*)d_ws;          // 256*128 floats
  float* b = w + UNITS * D;         // 256 floats

  const int n = in_sizes[0] / D;    // 131072

  prep_kernel<<<UNITS, D, 0, stream>>>(means, lnv, lprop, w, b, out);

  static_assert(STATS_ELEMS * sizeof(float) == 132096, "lds size");
  hipFuncSetAttribute((const void*)estep_kernel,
                      hipFuncAttributeMaxDynamicSharedMemorySize,
                      STATS_ELEMS * sizeof(float));
  estep_kernel<<<256, 1024, STATS_ELEMS * sizeof(float), stream>>>(
      features, cand, w, b, out, n);
}